// Round 1
// baseline (335.927 us; speedup 1.0000x reference)
//
#include <hip/hip_runtime.h>
#include <math.h>

// Problem shape (fixed by reference): x, identity: [8, 4096, 768] f32;
// scales: [768] f32. Output: 25165824 f32 + 1 f32 (z_scale).
static constexpr int kD = 768;
static constexpr int kRows = 8 * 4096;                 // 32768
static constexpr long long kN = (long long)kRows * kD; // 25165824
static constexpr int kVec = (int)(kN / 4);             // 6291456 float4s
static constexpr int kColGroups = kD / 4;              // 192 float4 columns

// ---------------------------------------------------------------------------
// Pass 1: amax = max |x + identity| over all elements.
// max(-min, max) == max of abs values, so one abs-max reduction suffices.
// Non-negative f32 bit patterns are monotonic as uint -> atomicMax on bits.
// ---------------------------------------------------------------------------
__global__ __launch_bounds__(256) void amax_kernel(
    const float4* __restrict__ x, const float4* __restrict__ idn,
    unsigned int* __restrict__ amax_bits)
{
    float m = 0.0f;
    const int stride = gridDim.x * blockDim.x;
    for (int i = blockIdx.x * blockDim.x + threadIdx.x; i < kVec; i += stride) {
        float4 a = x[i];
        float4 b = idn[i];
        m = fmaxf(m, fabsf(a.x + b.x));
        m = fmaxf(m, fabsf(a.y + b.y));
        m = fmaxf(m, fabsf(a.z + b.z));
        m = fmaxf(m, fabsf(a.w + b.w));
    }
    // wave64 reduction
    #pragma unroll
    for (int off = 32; off > 0; off >>= 1)
        m = fmaxf(m, __shfl_down(m, off, 64));
    if ((threadIdx.x & 63) == 0)
        atomicMax(amax_bits, __float_as_uint(m));
}

// Dyadic multiplier matching _batch_frexp exactly:
//   m, e = frexp(r); m_int = floor(m*2^31 + 0.5); factor = m_int * 2^(e-31)
// m_int <= 2^31 and the power-of-two scale are exact in f64, so
// rint(z_int * factor) == reference's round(z_int * m_int / 2^(31-e)).
__device__ inline double quant_factor(double r) {
    int e;
    double mm = frexp(r, &e);
    double m_int = floor(mm * 2147483648.0 + 0.5);
    return ldexp(m_int, e - 31);
}

__device__ inline float requant_elem(float xx, float ii, float p, float s,
                                     double fp, double fi, float z_scale) {
    float z_int = rintf(xx / p);   // f32 IEEE div + round-half-even, as ref
    float w_int = rintf(ii / s);
    double o  = rint((double)z_int * fp);   // exact product (<= 44 bits)
    double o1 = rint((double)w_int * fi);
    float q = (float)(o + o1);              // small integer, exact in f32
    q = fminf(fmaxf(q, -128.0f), 127.0f);
    return q * z_scale;
}

// ---------------------------------------------------------------------------
// Pass 2: elementwise requantize. Each thread owns a fixed group of 4
// columns (so the 8 frexp factors are computed once) and strides over rows.
// ---------------------------------------------------------------------------
__global__ __launch_bounds__(256) void quant_kernel(
    const float4* __restrict__ x, const float4* __restrict__ idn,
    const float4* __restrict__ pre, const float4* __restrict__ ids,
    const unsigned int* __restrict__ amax_bits,
    float4* __restrict__ out, float* __restrict__ out_scale)
{
    const float amax = __uint_as_float(*amax_bits);
    const float z_scale = fmaxf(amax / 127.0f, 1.1920928955078125e-07f);

    const int tid = blockIdx.x * blockDim.x + threadIdx.x;
    if (tid == 0) *out_scale = z_scale;

    const int cg = tid % kColGroups;
    const int row0 = tid / kColGroups;
    const int rowStride = (gridDim.x * blockDim.x) / kColGroups;

    const float4 pf = pre[cg];
    const float4 sf = ids[cg];
    const double zs = (double)z_scale;
    const double fp0 = quant_factor((double)pf.x / zs);
    const double fp1 = quant_factor((double)pf.y / zs);
    const double fp2 = quant_factor((double)pf.z / zs);
    const double fp3 = quant_factor((double)pf.w / zs);
    const double fi0 = quant_factor((double)sf.x / zs);
    const double fi1 = quant_factor((double)sf.y / zs);
    const double fi2 = quant_factor((double)sf.z / zs);
    const double fi3 = quant_factor((double)sf.w / zs);

    for (int row = row0; row < kRows; row += rowStride) {
        const int i = row * kColGroups + cg;
        float4 xv = x[i];
        float4 iv = idn[i];
        float4 ov;
        ov.x = requant_elem(xv.x, iv.x, pf.x, sf.x, fp0, fi0, z_scale);
        ov.y = requant_elem(xv.y, iv.y, pf.y, sf.y, fp1, fi1, z_scale);
        ov.z = requant_elem(xv.z, iv.z, pf.z, sf.z, fp2, fi2, z_scale);
        ov.w = requant_elem(xv.w, iv.w, pf.w, sf.w, fp3, fi3, z_scale);
        out[i] = ov;
    }
}

extern "C" void kernel_launch(void* const* d_in, const int* in_sizes, int n_in,
                              void* d_out, int out_size, void* d_ws, size_t ws_size,
                              hipStream_t stream) {
    const float* x   = (const float*)d_in[0];
    const float* pre = (const float*)d_in[1];
    const float* idn = (const float*)d_in[2];
    const float* ids = (const float*)d_in[3];
    float* out = (float*)d_out;

    unsigned int* amax_bits = (unsigned int*)d_ws;
    hipMemsetAsync(d_ws, 0, sizeof(unsigned int), stream);  // ws is poisoned 0xAA

    const int blocks = 1536;  // 6 blocks/CU; 16 grid-stride iters per thread
    amax_kernel<<<blocks, 256, 0, stream>>>(
        (const float4*)x, (const float4*)idn, amax_bits);
    quant_kernel<<<blocks, 256, 0, stream>>>(
        (const float4*)x, (const float4*)idn,
        (const float4*)pre, (const float4*)ids,
        amax_bits, (float4*)out, out + kN);
}

// Round 2
// 328.721 us; speedup vs baseline: 1.0219x; 1.0219x over previous
//
#include <hip/hip_runtime.h>
#include <math.h>

// Shape fixed by reference: x, identity: [8,4096,768] f32; scales [768] f32.
static constexpr int kD = 768;
static constexpr int kRows = 8 * 4096;                 // 32768
static constexpr long long kN = (long long)kRows * kD; // 25165824
static constexpr int kVec = (int)(kN / 4);             // 6291456 float4s
static constexpr int kColGroups = kD / 4;              // 192

// Grid choices (exact trip counts, no bounds checks):
//   amax : 2048 blk x 256 -> 524288 thr -> 12 f4/thread -> 3 outer x unroll 4
//   quant: 1536 blk x 256 -> 393216 thr (=192*2048) -> 16 f4/thread -> 4 x 4
static constexpr int kAmaxBlocks  = 2048;
static constexpr int kQuantBlocks = 1536;

// ---------------------------------------------------------------------------
// Pass 1: amax = max |x + identity|. Unroll 4: 8 independent 16B loads in
// flight per wave (vs 2 before) to beat the ~2-3k cycle loaded latency.
// ---------------------------------------------------------------------------
__global__ __launch_bounds__(256) void amax_kernel(
    const float4* __restrict__ x, const float4* __restrict__ idn,
    unsigned int* __restrict__ amax_bits)
{
    const int GS = kAmaxBlocks * 256;
    int i = blockIdx.x * blockDim.x + threadIdx.x;
    float m = 0.0f;
    #pragma unroll 1
    for (int outer = 0; outer < 3; ++outer) {
        float4 a0 = x[i];        float4 a1 = x[i + GS];
        float4 a2 = x[i + 2*GS]; float4 a3 = x[i + 3*GS];
        float4 b0 = idn[i];        float4 b1 = idn[i + GS];
        float4 b2 = idn[i + 2*GS]; float4 b3 = idn[i + 3*GS];
        m = fmaxf(m, fmaxf(fmaxf(fabsf(a0.x+b0.x), fabsf(a0.y+b0.y)),
                           fmaxf(fabsf(a0.z+b0.z), fabsf(a0.w+b0.w))));
        m = fmaxf(m, fmaxf(fmaxf(fabsf(a1.x+b1.x), fabsf(a1.y+b1.y)),
                           fmaxf(fabsf(a1.z+b1.z), fabsf(a1.w+b1.w))));
        m = fmaxf(m, fmaxf(fmaxf(fabsf(a2.x+b2.x), fabsf(a2.y+b2.y)),
                           fmaxf(fabsf(a2.z+b2.z), fabsf(a2.w+b2.w))));
        m = fmaxf(m, fmaxf(fmaxf(fabsf(a3.x+b3.x), fabsf(a3.y+b3.y)),
                           fmaxf(fabsf(a3.z+b3.z), fabsf(a3.w+b3.w))));
        i += 4 * GS;
    }
    #pragma unroll
    for (int off = 32; off > 0; off >>= 1)
        m = fmaxf(m, __shfl_down(m, off, 64));
    if ((threadIdx.x & 63) == 0)
        atomicMax(amax_bits, __float_as_uint(m));
}

// Dyadic multiplier matching _batch_frexp exactly:
//   m, e = frexp(r); m_int = floor(m*2^31 + 0.5); factor = m_int * 2^(e-31)
__device__ inline double quant_factor(double r) {
    int e;
    double mm = frexp(r, &e);
    double m_int = floor(mm * 2147483648.0 + 0.5);
    return ldexp(m_int, e - 31);
}

// ---------------------------------------------------------------------------
// Pass 1.5: per-column dyadic factors (768 of each) + z_scale output.
// Removes 8 f64 divides + frexp chains from every quant thread.
// ---------------------------------------------------------------------------
__global__ __launch_bounds__(256) void factor_kernel(
    const float* __restrict__ pre, const float* __restrict__ ids,
    const unsigned int* __restrict__ amax_bits,
    double* __restrict__ fp, double* __restrict__ fi,
    float* __restrict__ out_scale)
{
    const float amax = __uint_as_float(*amax_bits);
    const float z_scale = fmaxf(amax / 127.0f, 1.1920928955078125e-07f);
    const int d = blockIdx.x * blockDim.x + threadIdx.x;
    if (d == 0) *out_scale = z_scale;
    if (d < kD) {
        const double zs = (double)z_scale;
        fp[d] = quant_factor((double)pre[d] / zs);
        fi[d] = quant_factor((double)ids[d] / zs);
    }
}

__device__ inline float requant_elem(float xx, float ii, float p, float s,
                                     double fp, double fi, float z_scale) {
    float z_int = rintf(xx / p);            // IEEE f32 div + half-even, as ref
    float w_int = rintf(ii / s);
    double o  = rint((double)z_int * fp);   // exact f64 product (<= 44 bits)
    double o1 = rint((double)w_int * fi);
    float q = (float)(o + o1);
    q = fminf(fmaxf(q, -128.0f), 127.0f);
    return q * z_scale;
}

__device__ inline float4 requant4(float4 xv, float4 iv, float4 pf, float4 sf,
                                  const double* fp, const double* fi, float zs) {
    float4 ov;
    ov.x = requant_elem(xv.x, iv.x, pf.x, sf.x, fp[0], fi[0], zs);
    ov.y = requant_elem(xv.y, iv.y, pf.y, sf.y, fp[1], fi[1], zs);
    ov.z = requant_elem(xv.z, iv.z, pf.z, sf.z, fp[2], fi[2], zs);
    ov.w = requant_elem(xv.w, iv.w, pf.w, sf.w, fp[3], fi[3], zs);
    return ov;
}

// ---------------------------------------------------------------------------
// Pass 2: elementwise requantize. Grid-stride with stride % 192 == 0 so each
// thread's column group (and its 8 factors) is loop-invariant. Unroll 4.
// ---------------------------------------------------------------------------
__global__ __launch_bounds__(256) void quant_kernel(
    const float4* __restrict__ x, const float4* __restrict__ idn,
    const float4* __restrict__ pre, const float4* __restrict__ ids,
    const unsigned int* __restrict__ amax_bits,
    const double* __restrict__ fp_tab, const double* __restrict__ fi_tab,
    float4* __restrict__ out)
{
    const float amax = __uint_as_float(*amax_bits);
    const float z_scale = fmaxf(amax / 127.0f, 1.1920928955078125e-07f);

    const int GS = kQuantBlocks * 256;   // 393216 = 192 * 2048
    const int tid = blockIdx.x * blockDim.x + threadIdx.x;
    const int cg = tid % kColGroups;     // loop-invariant column group

    const float4 pf = pre[cg];
    const float4 sf = ids[cg];
    double fp[4], fi[4];
    #pragma unroll
    for (int j = 0; j < 4; ++j) { fp[j] = fp_tab[4*cg + j]; fi[j] = fi_tab[4*cg + j]; }

    int i = tid;
    #pragma unroll 1
    for (int outer = 0; outer < 4; ++outer) {
        const int i0 = i, i1 = i + GS, i2 = i + 2*GS, i3 = i + 3*GS;
        float4 x0 = x[i0], x1 = x[i1], x2 = x[i2], x3 = x[i3];
        float4 v0 = idn[i0], v1 = idn[i1], v2 = idn[i2], v3 = idn[i3];
        out[i0] = requant4(x0, v0, pf, sf, fp, fi, z_scale);
        out[i1] = requant4(x1, v1, pf, sf, fp, fi, z_scale);
        out[i2] = requant4(x2, v2, pf, sf, fp, fi, z_scale);
        out[i3] = requant4(x3, v3, pf, sf, fp, fi, z_scale);
        i += 4 * GS;
    }
}

extern "C" void kernel_launch(void* const* d_in, const int* in_sizes, int n_in,
                              void* d_out, int out_size, void* d_ws, size_t ws_size,
                              hipStream_t stream) {
    const float* x   = (const float*)d_in[0];
    const float* pre = (const float*)d_in[1];
    const float* idn = (const float*)d_in[2];
    const float* ids = (const float*)d_in[3];
    float* out = (float*)d_out;

    // ws layout: [0,4) amax bits; [64, 64+6144) fp table; then fi table.
    unsigned int* amax_bits = (unsigned int*)d_ws;
    double* fp_tab = (double*)((char*)d_ws + 64);
    double* fi_tab = fp_tab + kD;
    hipMemsetAsync(d_ws, 0, sizeof(unsigned int), stream);

    amax_kernel<<<kAmaxBlocks, 256, 0, stream>>>(
        (const float4*)x, (const float4*)idn, amax_bits);
    factor_kernel<<<3, 256, 0, stream>>>(pre, ids, amax_bits, fp_tab, fi_tab,
                                         out + kN);
    quant_kernel<<<kQuantBlocks, 256, 0, stream>>>(
        (const float4*)x, (const float4*)idn,
        (const float4*)pre, (const float4*)ids,
        amax_bits, fp_tab, fi_tab, (float4*)out);
}

// Round 4
// 323.910 us; speedup vs baseline: 1.0371x; 1.0149x over previous
//
#include <hip/hip_runtime.h>
#include <math.h>

// Shape fixed by reference: x, identity: [8,4096,768] f32; scales [768] f32.
static constexpr int kD = 768;
static constexpr int kRows = 8 * 4096;                 // 32768
static constexpr long long kN = (long long)kRows * kD; // 25165824
static constexpr int kVec = (int)(kN / 4);             // 6291456 float4s
static constexpr int kColGroups = kD / 4;              // 192

// amax : 2048 blk x 256 = 524288 thr -> 12 f4/thread = 2 batches of 6 pairs
// quant: 1536 blk x 256 = 393216 thr -> 16 f4/thread = 4 batches of 4 pairs
static constexpr int kAmaxBlocks  = 2048;
static constexpr int kQuantBlocks = 1536;

// Native clang vector type: __builtin_nontemporal_store requires it
// (HIP_vector_type float4 is a struct and is rejected).
typedef float nf4 __attribute__((ext_vector_type(4)));

// ---------------------------------------------------------------------------
// Pass 1: amax = max |x + identity|.
// Loads batched into register arrays BEFORE any consumption, with 4
// independent accumulators, so the scheduler keeps 12 dwordx4 in flight
// instead of sinking loads into a serial fmax chain (R2: VGPR=20, 1.7 TB/s).
// ---------------------------------------------------------------------------
__global__ __launch_bounds__(256, 4) void amax_kernel(
    const float4* __restrict__ x, const float4* __restrict__ idn,
    unsigned int* __restrict__ amax_bits)
{
    const int GS = kAmaxBlocks * 256;
    const int tid = blockIdx.x * blockDim.x + threadIdx.x;
    float4 m4 = make_float4(0.f, 0.f, 0.f, 0.f);

    #pragma unroll 1
    for (int outer = 0; outer < 2; ++outer) {
        const int base = tid + outer * 6 * GS;
        float4 a[6], b[6];
        #pragma unroll
        for (int j = 0; j < 6; ++j) a[j] = x[base + j * GS];
        #pragma unroll
        for (int j = 0; j < 6; ++j) b[j] = idn[base + j * GS];
        #pragma unroll
        for (int j = 0; j < 6; ++j) {
            m4.x = fmaxf(m4.x, fabsf(a[j].x + b[j].x));
            m4.y = fmaxf(m4.y, fabsf(a[j].y + b[j].y));
            m4.z = fmaxf(m4.z, fabsf(a[j].z + b[j].z));
            m4.w = fmaxf(m4.w, fabsf(a[j].w + b[j].w));
        }
    }
    float m = fmaxf(fmaxf(m4.x, m4.y), fmaxf(m4.z, m4.w));
    #pragma unroll
    for (int off = 32; off > 0; off >>= 1)
        m = fmaxf(m, __shfl_down(m, off, 64));
    if ((threadIdx.x & 63) == 0)
        atomicMax(amax_bits, __float_as_uint(m));
}

// Dyadic multiplier matching _batch_frexp exactly:
//   m, e = frexp(r); m_int = floor(m*2^31 + 0.5); factor = m_int * 2^(e-31)
__device__ inline double quant_factor(double r) {
    int e;
    double mm = frexp(r, &e);
    double m_int = floor(mm * 2147483648.0 + 0.5);
    return ldexp(m_int, e - 31);
}

// ---------------------------------------------------------------------------
// Pass 1.5: per-column dyadic factors (768 of each) + z_scale output.
// ---------------------------------------------------------------------------
__global__ __launch_bounds__(256) void factor_kernel(
    const float* __restrict__ pre, const float* __restrict__ ids,
    const unsigned int* __restrict__ amax_bits,
    double* __restrict__ fp, double* __restrict__ fi,
    float* __restrict__ out_scale)
{
    const float amax = __uint_as_float(*amax_bits);
    const float z_scale = fmaxf(amax / 127.0f, 1.1920928955078125e-07f);
    const int d = blockIdx.x * blockDim.x + threadIdx.x;
    if (d == 0) *out_scale = z_scale;
    if (d < kD) {
        const double zs = (double)z_scale;
        fp[d] = quant_factor((double)pre[d] / zs);
        fi[d] = quant_factor((double)ids[d] / zs);
    }
}

__device__ inline float requant_elem(float xx, float ii, float p, float s,
                                     double fp, double fi, float z_scale) {
    float z_int = rintf(xx / p);            // IEEE f32 div + half-even, as ref
    float w_int = rintf(ii / s);
    double o  = rint((double)z_int * fp);   // exact f64 product (<= 44 bits)
    double o1 = rint((double)w_int * fi);
    float q = (float)(o + o1);
    q = fminf(fmaxf(q, -128.0f), 127.0f);
    return q * z_scale;
}

// ---------------------------------------------------------------------------
// Pass 2: elementwise requantize. Stride % 192 == 0 keeps each thread's
// column group loop-invariant. Batches of 4 load-pairs (8 dwordx4 in
// flight) before compute; nontemporal stores (output never re-read,
// preserve L3 for x/idn).
// ---------------------------------------------------------------------------
__global__ __launch_bounds__(256, 4) void quant_kernel(
    const float4* __restrict__ x, const float4* __restrict__ idn,
    const float4* __restrict__ pre, const float4* __restrict__ ids,
    const unsigned int* __restrict__ amax_bits,
    const double* __restrict__ fp_tab, const double* __restrict__ fi_tab,
    nf4* __restrict__ out)
{
    const float amax = __uint_as_float(*amax_bits);
    const float z_scale = fmaxf(amax / 127.0f, 1.1920928955078125e-07f);

    const int GS = kQuantBlocks * 256;   // 393216 = 192 * 2048
    const int tid = blockIdx.x * blockDim.x + threadIdx.x;
    const int cg = tid % kColGroups;     // loop-invariant column group

    const float4 pf = pre[cg];
    const float4 sf = ids[cg];
    double fp[4], fi[4];
    #pragma unroll
    for (int j = 0; j < 4; ++j) { fp[j] = fp_tab[4*cg + j]; fi[j] = fi_tab[4*cg + j]; }

    #pragma unroll 1
    for (int outer = 0; outer < 4; ++outer) {
        const int base = tid + outer * 4 * GS;
        float4 xa[4], ia[4];
        #pragma unroll
        for (int j = 0; j < 4; ++j) xa[j] = x[base + j * GS];
        #pragma unroll
        for (int j = 0; j < 4; ++j) ia[j] = idn[base + j * GS];
        #pragma unroll
        for (int j = 0; j < 4; ++j) {
            nf4 ov;
            ov.x = requant_elem(xa[j].x, ia[j].x, pf.x, sf.x, fp[0], fi[0], z_scale);
            ov.y = requant_elem(xa[j].y, ia[j].y, pf.y, sf.y, fp[1], fi[1], z_scale);
            ov.z = requant_elem(xa[j].z, ia[j].z, pf.z, sf.z, fp[2], fi[2], z_scale);
            ov.w = requant_elem(xa[j].w, ia[j].w, pf.w, sf.w, fp[3], fi[3], z_scale);
            __builtin_nontemporal_store(ov, &out[base + j * GS]);
        }
    }
}

extern "C" void kernel_launch(void* const* d_in, const int* in_sizes, int n_in,
                              void* d_out, int out_size, void* d_ws, size_t ws_size,
                              hipStream_t stream) {
    const float* x   = (const float*)d_in[0];
    const float* pre = (const float*)d_in[1];
    const float* idn = (const float*)d_in[2];
    const float* ids = (const float*)d_in[3];
    float* out = (float*)d_out;

    // ws layout: [0,4) amax bits; [64, 64+6144) fp table; then fi table.
    unsigned int* amax_bits = (unsigned int*)d_ws;
    double* fp_tab = (double*)((char*)d_ws + 64);
    double* fi_tab = fp_tab + kD;
    (void)hipMemsetAsync(d_ws, 0, sizeof(unsigned int), stream);

    amax_kernel<<<kAmaxBlocks, 256, 0, stream>>>(
        (const float4*)x, (const float4*)idn, amax_bits);
    factor_kernel<<<3, 256, 0, stream>>>(pre, ids, amax_bits, fp_tab, fi_tab,
                                         out + kN);
    quant_kernel<<<kQuantBlocks, 256, 0, stream>>>(
        (const float4*)x, (const float4*)idn,
        (const float4*)pre, (const float4*)ids,
        amax_bits, fp_tab, fi_tab, (nf4*)out);
}

// Round 5
// 309.917 us; speedup vs baseline: 1.0839x; 1.0452x over previous
//
#include <hip/hip_runtime.h>
#include <math.h>

// Shape fixed by reference: x, identity: [8,4096,768] f32; scales [768] f32.
static constexpr int kD = 768;
static constexpr int kRows = 32768;
static constexpr long long kN = (long long)kRows * kD;  // 25165824
static constexpr int kColGroups = 192;                  // float4s per row (3 KB)
static constexpr int kBlocks = 2048;
static constexpr int kRowsPerBlock = 16;                // 16 rows x 3KB = 48KB/block

typedef float nf4 __attribute__((ext_vector_type(4)));

// Layout: 192-thread blocks (3 waves). threadIdx.x IS the f4-column, so each
// wave reads a contiguous 1KB line per instruction and the per-thread column
// (and its dyadic factors) is loop-invariant. Each block sweeps 16 contiguous
// rows (48KB contiguous footprint) -> DRAM page locality, unlike the R1-R4
// grid-stride scatter (8MB hops) that pinned reads at ~1.8 TB/s.
// XCD swizzle: blocks dispatch round-robin by blockIdx%8; regroup so each XCD
// sweeps a contiguous 1/8 of memory (8 clean sequential streams).
__device__ __forceinline__ int swizzled_block() {
    return (int)((blockIdx.x & 7) * (kBlocks >> 3) + (blockIdx.x >> 3));
}

// ---------------------------------------------------------------------------
// Pass 1: amax = max |x + identity|.
// ---------------------------------------------------------------------------
__global__ __launch_bounds__(192, 4) void amax_kernel(
    const float4* __restrict__ x, const float4* __restrict__ idn,
    unsigned int* __restrict__ amax_bits)
{
    const int b = swizzled_block();
    const int t = threadIdx.x;  // f4-column 0..191
    const int base = b * (kRowsPerBlock * kColGroups) + t;

    float4 m4 = make_float4(0.f, 0.f, 0.f, 0.f);
    #pragma unroll 1
    for (int outer = 0; outer < 4; ++outer) {
        const int rb = base + outer * 4 * kColGroups;
        float4 a[4], c[4];
        #pragma unroll
        for (int j = 0; j < 4; ++j) a[j] = x[rb + j * kColGroups];
        #pragma unroll
        for (int j = 0; j < 4; ++j) c[j] = idn[rb + j * kColGroups];
        __builtin_amdgcn_sched_barrier(0);  // keep all 8 loads in flight
        #pragma unroll
        for (int j = 0; j < 4; ++j) {
            m4.x = fmaxf(m4.x, fabsf(a[j].x + c[j].x));
            m4.y = fmaxf(m4.y, fabsf(a[j].y + c[j].y));
            m4.z = fmaxf(m4.z, fabsf(a[j].z + c[j].z));
            m4.w = fmaxf(m4.w, fabsf(a[j].w + c[j].w));
        }
        __builtin_amdgcn_sched_barrier(0);
    }
    float m = fmaxf(fmaxf(m4.x, m4.y), fmaxf(m4.z, m4.w));
    #pragma unroll
    for (int off = 32; off > 0; off >>= 1)
        m = fmaxf(m, __shfl_down(m, off, 64));
    if ((threadIdx.x & 63) == 0)
        atomicMax(amax_bits, __float_as_uint(m));
}

// Dyadic multiplier matching _batch_frexp exactly:
//   m, e = frexp(r); m_int = floor(m*2^31 + 0.5); factor = m_int * 2^(e-31)
__device__ inline double quant_factor(double r) {
    int e;
    double mm = frexp(r, &e);
    double m_int = floor(mm * 2147483648.0 + 0.5);
    return ldexp(m_int, e - 31);
}

// ---------------------------------------------------------------------------
// Pass 1.5: per-column dyadic factors (768 of each) + z_scale output.
// ---------------------------------------------------------------------------
__global__ __launch_bounds__(256) void factor_kernel(
    const float* __restrict__ pre, const float* __restrict__ ids,
    const unsigned int* __restrict__ amax_bits,
    double* __restrict__ fp, double* __restrict__ fi,
    float* __restrict__ out_scale)
{
    const float amax = __uint_as_float(*amax_bits);
    const float z_scale = fmaxf(amax / 127.0f, 1.1920928955078125e-07f);
    const int d = blockIdx.x * blockDim.x + threadIdx.x;
    if (d == 0) *out_scale = z_scale;
    if (d < kD) {
        const double zs = (double)z_scale;
        fp[d] = quant_factor((double)pre[d] / zs);
        fi[d] = quant_factor((double)ids[d] / zs);
    }
}

__device__ inline float requant_elem(float xx, float ii, float p, float s,
                                     double fp, double fi, float z_scale) {
    float z_int = rintf(xx / p);            // IEEE f32 div + half-even, as ref
    float w_int = rintf(ii / s);
    double o  = rint((double)z_int * fp);   // exact f64 product (<= 44 bits)
    double o1 = rint((double)w_int * fi);
    float q = (float)(o + o1);
    q = fminf(fmaxf(q, -128.0f), 127.0f);
    return q * z_scale;
}

// ---------------------------------------------------------------------------
// Pass 2: elementwise requantize, same row-sweep layout. Column (= factors)
// loop-invariant per thread; nt stores (output never re-read).
// ---------------------------------------------------------------------------
__global__ __launch_bounds__(192, 4) void quant_kernel(
    const float4* __restrict__ x, const float4* __restrict__ idn,
    const float4* __restrict__ pre, const float4* __restrict__ ids,
    const unsigned int* __restrict__ amax_bits,
    const double* __restrict__ fp_tab, const double* __restrict__ fi_tab,
    nf4* __restrict__ out)
{
    const float amax = __uint_as_float(*amax_bits);
    const float z_scale = fmaxf(amax / 127.0f, 1.1920928955078125e-07f);

    const int b = swizzled_block();
    const int t = threadIdx.x;  // f4-column = column group
    const int base = b * (kRowsPerBlock * kColGroups) + t;

    const float4 pf = pre[t];
    const float4 sf = ids[t];
    double fp[4], fi[4];
    #pragma unroll
    for (int j = 0; j < 4; ++j) { fp[j] = fp_tab[4*t + j]; fi[j] = fi_tab[4*t + j]; }

    #pragma unroll 1
    for (int outer = 0; outer < 4; ++outer) {
        const int rb = base + outer * 4 * kColGroups;
        float4 xa[4], ia[4];
        #pragma unroll
        for (int j = 0; j < 4; ++j) xa[j] = x[rb + j * kColGroups];
        #pragma unroll
        for (int j = 0; j < 4; ++j) ia[j] = idn[rb + j * kColGroups];
        __builtin_amdgcn_sched_barrier(0);  // keep all 8 loads in flight
        #pragma unroll
        for (int j = 0; j < 4; ++j) {
            nf4 ov;
            ov.x = requant_elem(xa[j].x, ia[j].x, pf.x, sf.x, fp[0], fi[0], z_scale);
            ov.y = requant_elem(xa[j].y, ia[j].y, pf.y, sf.y, fp[1], fi[1], z_scale);
            ov.z = requant_elem(xa[j].z, ia[j].z, pf.z, sf.z, fp[2], fi[2], z_scale);
            ov.w = requant_elem(xa[j].w, ia[j].w, pf.w, sf.w, fp[3], fi[3], z_scale);
            __builtin_nontemporal_store(ov, &out[rb + j * kColGroups]);
        }
        __builtin_amdgcn_sched_barrier(0);
    }
}

extern "C" void kernel_launch(void* const* d_in, const int* in_sizes, int n_in,
                              void* d_out, int out_size, void* d_ws, size_t ws_size,
                              hipStream_t stream) {
    const float* x   = (const float*)d_in[0];
    const float* pre = (const float*)d_in[1];
    const float* idn = (const float*)d_in[2];
    const float* ids = (const float*)d_in[3];
    float* out = (float*)d_out;

    // ws layout: [0,4) amax bits; [64, 64+6144) fp table; then fi table.
    unsigned int* amax_bits = (unsigned int*)d_ws;
    double* fp_tab = (double*)((char*)d_ws + 64);
    double* fi_tab = fp_tab + kD;
    (void)hipMemsetAsync(d_ws, 0, sizeof(unsigned int), stream);

    amax_kernel<<<kBlocks, 192, 0, stream>>>(
        (const float4*)x, (const float4*)idn, amax_bits);
    factor_kernel<<<3, 256, 0, stream>>>(pre, ids, amax_bits, fp_tab, fi_tab,
                                         out + kN);
    quant_kernel<<<kBlocks, 192, 0, stream>>>(
        (const float4*)x, (const float4*)idn,
        (const float4*)pre, (const float4*)ids,
        amax_bits, fp_tab, fi_tab, (nf4*)out);
}